// Round 6
// baseline (575.951 us; speedup 1.0000x reference)
//
#include <hip/hip_runtime.h>

#define BN_EPS 1e-5f

// ws layout (floats):
//   stats[0..28)   sum1      [28..56)  ssq1
//   stats[56..64)  sum2      [64..72)  ssq2
//   stats[72..100) scale1    [100..128) shift1
//   stats[128..136) scale2   [136..144) shift2
//   Psrc at ws+256          (N*32, rows 128B-aligned, cols 28..31 zeroed)
//   y1   at Psrc + N*32     (E*28)
//   y2   at y1 + E*28       (E*8)
//   Pdst OVERLAPS y2        (N*32 <= E*8; Pdst dead before K4 writes y2)

// K1: thread-per-node, 28 channels per thread, two blocks per 256-node range
// (blockIdx&1 selects which half of W1's k-range -> Psrc or Pdst row).
__global__ void k1_proj(const float* __restrict__ h, const float* __restrict__ W1,
                        float* __restrict__ Psrc, float* __restrict__ Pdst,
                        float* __restrict__ stats, int N) {
  if (blockIdx.x == 0 && threadIdx.x < 72) stats[threadIdx.x] = 0.f;
  const int half = blockIdx.x & 1;            // 0: src half (k 0..128), 1: dst half
  const int node = (blockIdx.x >> 1) * 256 + threadIdx.x;
  if (node >= N) return;

  const float* __restrict__ wbase = W1 + half * 128;  // + c*268 + k
  const float4* __restrict__ h4 = (const float4*)(h + (size_t)node * 128);

  float acc[28];
#pragma unroll
  for (int c = 0; c < 28; c++) acc[c] = 0.f;

  for (int kk = 0; kk < 16; kk++) {
    const float4 a = h4[kk * 2];
    const float4 b = h4[kk * 2 + 1];
#pragma unroll
    for (int c = 0; c < 28; c++) {
      const float* w = wbase + c * 268 + kk * 8;  // uniform address -> s_load
      acc[c] += a.x * w[0] + a.y * w[1] + a.z * w[2] + a.w * w[3]
              + b.x * w[4] + b.y * w[5] + b.z * w[6] + b.w * w[7];
    }
  }

  float4* po = (float4*)((half ? Pdst : Psrc) + (size_t)node * 32);
#pragma unroll
  for (int q = 0; q < 7; q++) {
    po[q] = make_float4(acc[q * 4], acc[q * 4 + 1], acc[q * 4 + 2], acc[q * 4 + 3]);
  }
  po[7] = make_float4(0.f, 0.f, 0.f, 0.f);  // zero pad (rows 128B, single-line gathers)
}

// K2 (edge-per-lane rewrite): one thread = one edge, all 28 channels.
// WHY: rounds 1/4/5 proved channel-per-lane k2 is serialized by lgkmcnt(0)
// drains — the uniform ef loads become out-of-order SMEM s_loads, and every
// use forces a full scalar-queue drain, collapsing any software pipeline.
// Here ALL loads are per-lane vector loads (in-order vmcnt, partial waits):
// 2 idx + 7 pa + 7 pb + 3 ef float4 = 17 independent loads per edge.
// W1's ef-columns are staged in LDS (uniform broadcast ds_read, in-order).
// y1 stores: lane e writes row e -> wave covers 7168B contiguous, full lines,
// no write-RMW. Stats: 56 per-lane accumulators (static indices), one
// shfl-xor tree + 56 atomics per block.
__global__ __launch_bounds__(256, 3)
void k2_edge(const float* __restrict__ Psrc, const float* __restrict__ Pdst,
             const float* __restrict__ ef,
             const int* __restrict__ src, const int* __restrict__ dst,
             const float* __restrict__ W1, const float* __restrict__ b1,
             float* __restrict__ y1, float* __restrict__ stats, int E) {
  __shared__ float lw[28][12];   // ef-part of W1 (cols 256..268 of each row)
  __shared__ float lb[28];
  for (int i = threadIdx.x; i < 336; i += 256) {
    lw[i / 12][i % 12] = W1[(i / 12) * 268 + 256 + (i % 12)];
  }
  if (threadIdx.x < 28) lb[threadIdx.x] = b1[threadIdx.x];
  __syncthreads();

  float sumL[28], ssqL[28];
#pragma unroll
  for (int c = 0; c < 28; c++) { sumL[c] = 0.f; ssqL[c] = 0.f; }

  const int stride = gridDim.x * 256;
  for (int e = blockIdx.x * 256 + threadIdx.x; e < E; e += stride) {
    const int s = src[e], d = dst[e];
    const float4* pa4 = (const float4*)(Psrc + (size_t)s * 32);
    const float4* pb4 = (const float4*)(Pdst + (size_t)d * 32);
    const float4* e4 = (const float4*)(ef + (size_t)e * 12);

    float pa[28], pb[28], f[12];
#pragma unroll
    for (int q = 0; q < 7; q++) {
      const float4 t = pa4[q];
      pa[q * 4] = t.x; pa[q * 4 + 1] = t.y; pa[q * 4 + 2] = t.z; pa[q * 4 + 3] = t.w;
    }
#pragma unroll
    for (int q = 0; q < 7; q++) {
      const float4 t = pb4[q];
      pb[q * 4] = t.x; pb[q * 4 + 1] = t.y; pb[q * 4 + 2] = t.z; pb[q * 4 + 3] = t.w;
    }
#pragma unroll
    for (int q = 0; q < 3; q++) {
      const float4 t = e4[q];
      f[q * 4] = t.x; f[q * 4 + 1] = t.y; f[q * 4 + 2] = t.z; f[q * 4 + 3] = t.w;
    }

    float v[28];
#pragma unroll
    for (int c = 0; c < 28; c++) {
      const float4* lw4 = (const float4*)(&lw[c][0]);  // uniform -> broadcast
      const float4 w0 = lw4[0], w1 = lw4[1], w2 = lw4[2];
      float acc = lb[c]
          + f[0] * w0.x + f[1] * w0.y + f[2] * w0.z + f[3] * w0.w
          + f[4] * w1.x + f[5] * w1.y + f[6] * w1.z + f[7] * w1.w
          + f[8] * w2.x + f[9] * w2.y + f[10] * w2.z + f[11] * w2.w;
      acc += pa[c] + pb[c];
      v[c] = acc;
      sumL[c] += acc;
      ssqL[c] += acc * acc;
    }

    float4* yo = (float4*)(y1 + (size_t)e * 28);
#pragma unroll
    for (int q = 0; q < 7; q++) {
      yo[q] = make_float4(v[q * 4], v[q * 4 + 1], v[q * 4 + 2], v[q * 4 + 3]);
    }
  }

  // block reduction: shfl-xor tree per channel, then per-wave LDS, 56 atomics
  __shared__ float redS[4][28];
  __shared__ float redQ[4][28];
  const int wave = threadIdx.x >> 6, lane = threadIdx.x & 63;
#pragma unroll
  for (int c = 0; c < 28; c++) {
    float s = sumL[c], q = ssqL[c];
    for (int off = 32; off; off >>= 1) {
      s += __shfl_xor(s, off);
      q += __shfl_xor(q, off);
    }
    if (lane == 0) { redS[wave][c] = s; redQ[wave][c] = q; }
  }
  __syncthreads();
  if (threadIdx.x < 28) {
    const int c = threadIdx.x;
    atomicAdd(&stats[c], redS[0][c] + redS[1][c] + redS[2][c] + redS[3][c]);
    atomicAdd(&stats[28 + c], redQ[0][c] + redQ[1][c] + redQ[2][c] + redQ[3][c]);
  }
}

// K3: finalize BN1 -> scale1/shift1
__global__ void k3_fin1(const float* __restrict__ gamma, const float* __restrict__ beta,
                        float* __restrict__ stats, float invE) {
  const int c = threadIdx.x;
  if (c < 28) {
    const float mean = stats[c] * invE;
    const float var = stats[28 + c] * invE - mean * mean;
    const float sc = gamma[c] * rsqrtf(var + BN_EPS);
    stats[72 + c] = sc;
    stats[100 + c] = beta[c] - mean * sc;
  }
}

// K4: s1 = relu(BN1(y1)); y2 = s1@W2.T + b2; accumulate stats2.
// LDS-staged 256-edge tiles: coalesced float4 global loads, rows padded to
// 29 floats (29 coprime 32 -> conflict-free b32 reads).
__global__ void k4_l2(const float* __restrict__ y1, const float* __restrict__ statsRO,
                      const float* __restrict__ W2, const float* __restrict__ b2,
                      float* __restrict__ y2, float* __restrict__ statsW, int E) {
  __shared__ float tile[256 * 29];  // 29696 B
  float as[8], aq[8];
#pragma unroll
  for (int o = 0; o < 8; o++) { as[o] = 0.f; aq[o] = 0.f; }

  for (int tileBase = blockIdx.x * 256; tileBase < E; tileBase += gridDim.x * 256) {
    const int nEdge = min(256, E - tileBase);
    const int total = nEdge * 28;
    const float* gp = y1 + (size_t)tileBase * 28;
    for (int j = threadIdx.x * 4; j < total; j += 1024) {
      const float4 v = *(const float4*)(gp + j);
      const int e = j / 28;
      const int cc = j - e * 28;
      float* lr = &tile[e * 29 + cc];
      lr[0] = v.x; lr[1] = v.y; lr[2] = v.z; lr[3] = v.w;
    }
    __syncthreads();
    if ((int)threadIdx.x < nEdge) {
      const float* s1 = &tile[threadIdx.x * 29];
      float acc[8];
#pragma unroll
      for (int o = 0; o < 8; o++) acc[o] = b2[o];
#pragma unroll
      for (int cc = 0; cc < 28; cc++) {
        const float s = fmaxf(s1[cc] * statsRO[72 + cc] + statsRO[100 + cc], 0.f);
#pragma unroll
        for (int o = 0; o < 8; o++) acc[o] += W2[o * 28 + cc] * s;  // uniform -> s_load
      }
      float4* yo = (float4*)(y2 + (size_t)(tileBase + threadIdx.x) * 8);
      yo[0] = make_float4(acc[0], acc[1], acc[2], acc[3]);
      yo[1] = make_float4(acc[4], acc[5], acc[6], acc[7]);
#pragma unroll
      for (int o = 0; o < 8; o++) { as[o] += acc[o]; aq[o] += acc[o] * acc[o]; }
    }
    __syncthreads();  // before next tile overwrite
  }

#pragma unroll
  for (int o = 0; o < 8; o++) {
    for (int off = 32; off; off >>= 1) {
      as[o] += __shfl_down(as[o], off);
      aq[o] += __shfl_down(aq[o], off);
    }
  }
  __shared__ float redS[4][16];
  const int wave = threadIdx.x >> 6, lane = threadIdx.x & 63;
  if (lane == 0) {
#pragma unroll
    for (int o = 0; o < 8; o++) { redS[wave][o] = as[o]; redS[wave][8 + o] = aq[o]; }
  }
  __syncthreads();
  if (threadIdx.x < 16) {
    const int t = threadIdx.x;
    atomicAdd(&statsW[56 + t], redS[0][t] + redS[1][t] + redS[2][t] + redS[3][t]);
  }
}

// K5: finalize BN2 -> scale2/shift2
__global__ void k5_fin2(const float* __restrict__ gamma, const float* __restrict__ beta,
                        float* __restrict__ stats, float invE) {
  const int c = threadIdx.x;
  if (c < 8) {
    const float mean = stats[56 + c] * invE;
    const float var = stats[64 + c] * invE - mean * mean;
    const float sc = gamma[c] * rsqrtf(var + BN_EPS);
    stats[128 + c] = sc;
    stats[136 + c] = beta[c] - mean * sc;
  }
}

// K6: out = relu(BN2(y2)) @ W3.T + b3
__global__ void k6_l3(const float* __restrict__ y2, const float* __restrict__ stats,
                      const float* __restrict__ W3, const float* __restrict__ b3,
                      float* __restrict__ out, int E) {
  const int e = blockIdx.x * blockDim.x + threadIdx.x;
  if (e >= E) return;
  const float4* p = (const float4*)(y2 + (size_t)e * 8);
  float4 a = p[0], b4 = p[1];
  float v[8] = {a.x, a.y, a.z, a.w, b4.x, b4.y, b4.z, b4.w};
  float acc = b3[0];
#pragma unroll
  for (int o = 0; o < 8; o++) {
    float s = fmaxf(v[o] * stats[128 + o] + stats[136 + o], 0.f);
    acc += W3[o] * s;
  }
  out[e] = acc;
}

extern "C" void kernel_launch(void* const* d_in, const int* in_sizes, int n_in,
                              void* d_out, int out_size, void* d_ws, size_t ws_size,
                              hipStream_t stream) {
  const float* h   = (const float*)d_in[0];
  const float* ef  = (const float*)d_in[1];
  const int* src   = (const int*)d_in[2];
  const int* dst   = (const int*)d_in[3];
  const float* W1  = (const float*)d_in[4];
  const float* b1  = (const float*)d_in[5];
  const float* g1  = (const float*)d_in[6];
  const float* be1 = (const float*)d_in[7];
  const float* W2  = (const float*)d_in[8];
  const float* b2  = (const float*)d_in[9];
  const float* g2  = (const float*)d_in[10];
  const float* be2 = (const float*)d_in[11];
  const float* W3  = (const float*)d_in[12];
  const float* b3  = (const float*)d_in[13];
  float* out = (float*)d_out;

  const int N = in_sizes[0] / 128;
  const int E = in_sizes[2];
  const float invE = 1.0f / (float)E;

  float* ws = (float*)d_ws;
  float* stats = ws;                    // 256 floats reserved
  float* Psrc = ws + 256;               // N*32, 128B-aligned rows
  float* y1 = Psrc + (size_t)N * 32;    // E*28
  float* y2 = y1 + (size_t)E * 28;      // E*8
  float* Pdst = y2;                     // overlap: Pdst dead before K4 writes y2

  const int nodeBlocks = (N + 255) / 256;
  const int nTiles = (E + 255) / 256;
  k1_proj<<<nodeBlocks * 2, 256, 0, stream>>>(h, W1, Psrc, Pdst, stats, N);
  k2_edge<<<1172, 256, 0, stream>>>(Psrc, Pdst, ef, src, dst, W1, b1, y1, stats, E);
  k3_fin1<<<1, 32, 0, stream>>>(g1, be1, stats, invE);
  k4_l2<<<nTiles, 256, 0, stream>>>(y1, stats, W2, b2, y2, stats, E);
  k5_fin2<<<1, 64, 0, stream>>>(g2, be2, stats, invE);
  k6_l3<<<nTiles, 256, 0, stream>>>(y2, stats, W3, b3, out, E);
}

// Round 7
// 350.691 us; speedup vs baseline: 1.6423x; 1.6423x over previous
//
#include <hip/hip_runtime.h>

#define BN_EPS 1e-5f

// ws layout (floats):
//   stats[0..28)   sum1      [28..56)  ssq1
//   stats[56..64)  sum2      [64..72)  ssq2
//   stats[72..100) scale1    [100..128) shift1
//   stats[128..136) scale2   [136..144) shift2
//   Psrc at ws+256          (N*32, rows 128B-aligned, cols 28..31 zeroed)
//   y1   at Psrc + N*32     (E*28)
//   y2   at y1 + E*28       (E*8)
//   Pdst OVERLAPS y2        (N*32 <= E*8; Pdst dead before K4 writes y2)

// K1: thread-per-node, 28 channels per thread, two blocks per 256-node range.
__global__ void k1_proj(const float* __restrict__ h, const float* __restrict__ W1,
                        float* __restrict__ Psrc, float* __restrict__ Pdst,
                        float* __restrict__ stats, int N) {
  if (blockIdx.x == 0 && threadIdx.x < 72) stats[threadIdx.x] = 0.f;
  const int half = blockIdx.x & 1;            // 0: src half (k 0..128), 1: dst half
  const int node = (blockIdx.x >> 1) * 256 + threadIdx.x;
  if (node >= N) return;

  const float* __restrict__ wbase = W1 + half * 128;  // + c*268 + k
  const float4* __restrict__ h4 = (const float4*)(h + (size_t)node * 128);

  float acc[28];
#pragma unroll
  for (int c = 0; c < 28; c++) acc[c] = 0.f;

  for (int kk = 0; kk < 16; kk++) {
    const float4 a = h4[kk * 2];
    const float4 b = h4[kk * 2 + 1];
#pragma unroll
    for (int c = 0; c < 28; c++) {
      const float* w = wbase + c * 268 + kk * 8;  // uniform address -> s_load
      acc[c] += a.x * w[0] + a.y * w[1] + a.z * w[2] + a.w * w[3]
              + b.x * w[4] + b.y * w[5] + b.z * w[6] + b.w * w[7];
    }
  }

  float4* po = (float4*)((half ? Pdst : Psrc) + (size_t)node * 32);
#pragma unroll
  for (int q = 0; q < 7; q++) {
    po[q] = make_float4(acc[q * 4], acc[q * 4 + 1], acc[q * 4 + 2], acc[q * 4 + 3]);
  }
  po[7] = make_float4(0.f, 0.f, 0.f, 0.f);  // zero pad
}

// K2 (edge-per-lane, STATS-FREE): one thread = one edge, all 28 channels,
// consumed in 4-channel groups so the live set stays ~50 VGPR (round 6's
// spill came from the 56 per-lane stats accumulators + 3x28 arrays; stats
// now live in k2b). All loads per-lane vector loads (in-order vmcnt):
// idx(2) + 7 pa4 + 7 pb4 + 3 ef4; W1 ef-cols broadcast from LDS.
// One edge per thread total (grid = ceil(E/256)) -> 9 waves/SIMD.
__global__ void k2_edge(const float* __restrict__ Psrc, const float* __restrict__ Pdst,
                        const float* __restrict__ ef,
                        const int* __restrict__ src, const int* __restrict__ dst,
                        const float* __restrict__ W1, const float* __restrict__ b1,
                        float* __restrict__ y1, int E) {
  __shared__ float lw[28][12];   // ef-part of W1 (cols 256..268)
  __shared__ float lb[28];
  for (int i = threadIdx.x; i < 336; i += 256) {
    lw[i / 12][i % 12] = W1[(i / 12) * 268 + 256 + (i % 12)];
  }
  if (threadIdx.x < 28) lb[threadIdx.x] = b1[threadIdx.x];
  __syncthreads();

  const int e = blockIdx.x * 256 + threadIdx.x;
  if (e >= E) return;

  const int s = src[e], d = dst[e];
  const float4* __restrict__ pa4 = (const float4*)(Psrc + (size_t)s * 32);
  const float4* __restrict__ pb4 = (const float4*)(Pdst + (size_t)d * 32);
  const float4* __restrict__ e4 = (const float4*)(ef + (size_t)e * 12);

  float f[12];
#pragma unroll
  for (int q = 0; q < 3; q++) {
    const float4 t = e4[q];
    f[q * 4] = t.x; f[q * 4 + 1] = t.y; f[q * 4 + 2] = t.z; f[q * 4 + 3] = t.w;
  }

  float4* __restrict__ yo = (float4*)(y1 + (size_t)e * 28);
#pragma unroll
  for (int q = 0; q < 7; q++) {
    const float4 ta = pa4[q];
    const float4 tb = pb4[q];
    float acc[4];
#pragma unroll
    for (int i = 0; i < 4; i++) {
      const int c = q * 4 + i;
      const float* w = &lw[c][0];   // wave-uniform LDS -> broadcast ds_read
      acc[i] = lb[c]
          + f[0] * w[0] + f[1] * w[1] + f[2] * w[2] + f[3] * w[3]
          + f[4] * w[4] + f[5] * w[5] + f[6] * w[6] + f[7] * w[7]
          + f[8] * w[8] + f[9] * w[9] + f[10] * w[10] + f[11] * w[11];
    }
    yo[q] = make_float4(acc[0] + ta.x + tb.x, acc[1] + ta.y + tb.y,
                        acc[2] + ta.z + tb.z, acc[3] + ta.w + tb.w);
  }
}

// K2b: BN1 stats over y1, fully coalesced. Block = 224 threads so each
// thread's float4 slot has a FIXED channel group c0 = (4t)%28 (stride
// 1172*896 floats == 0 mod 28) -> 8 register accumulators per thread.
// LDS reduce (ds atomics, once per block), then 56 global atomics.
__global__ void k2b_stats(const float* __restrict__ y1, float* __restrict__ stats,
                          long long T /* = E*28 */) {
  __shared__ float lsum[28], lssq[28];
  if (threadIdx.x < 28) { lsum[threadIdx.x] = 0.f; lssq[threadIdx.x] = 0.f; }
  __syncthreads();

  float s4x = 0.f, s4y = 0.f, s4z = 0.f, s4w = 0.f;
  float q4x = 0.f, q4y = 0.f, q4z = 0.f, q4w = 0.f;
  const long long stride = (long long)gridDim.x * 224 * 4;
  for (long long j = ((long long)blockIdx.x * 224 + threadIdx.x) * 4; j < T; j += stride) {
    const float4 v = *(const float4*)(y1 + j);
    s4x += v.x; s4y += v.y; s4z += v.z; s4w += v.w;
    q4x += v.x * v.x; q4y += v.y * v.y; q4z += v.z * v.z; q4w += v.w * v.w;
  }
  const int c0 = (threadIdx.x * 4) % 28;
  atomicAdd(&lsum[c0], s4x);     atomicAdd(&lssq[c0], q4x);
  atomicAdd(&lsum[c0 + 1], s4y); atomicAdd(&lssq[c0 + 1], q4y);
  atomicAdd(&lsum[c0 + 2], s4z); atomicAdd(&lssq[c0 + 2], q4z);
  atomicAdd(&lsum[c0 + 3], s4w); atomicAdd(&lssq[c0 + 3], q4w);
  __syncthreads();
  if (threadIdx.x < 28) {
    atomicAdd(&stats[threadIdx.x], lsum[threadIdx.x]);
    atomicAdd(&stats[28 + threadIdx.x], lssq[threadIdx.x]);
  }
}

// K3: finalize BN1 -> scale1/shift1
__global__ void k3_fin1(const float* __restrict__ gamma, const float* __restrict__ beta,
                        float* __restrict__ stats, float invE) {
  const int c = threadIdx.x;
  if (c < 28) {
    const float mean = stats[c] * invE;
    const float var = stats[28 + c] * invE - mean * mean;
    const float sc = gamma[c] * rsqrtf(var + BN_EPS);
    stats[72 + c] = sc;
    stats[100 + c] = beta[c] - mean * sc;
  }
}

// K4: s1 = relu(BN1(y1)); y2 = s1@W2.T + b2; accumulate stats2.
__global__ void k4_l2(const float* __restrict__ y1, const float* __restrict__ statsRO,
                      const float* __restrict__ W2, const float* __restrict__ b2,
                      float* __restrict__ y2, float* __restrict__ statsW, int E) {
  __shared__ float tile[256 * 29];  // 29696 B
  float as[8], aq[8];
#pragma unroll
  for (int o = 0; o < 8; o++) { as[o] = 0.f; aq[o] = 0.f; }

  for (int tileBase = blockIdx.x * 256; tileBase < E; tileBase += gridDim.x * 256) {
    const int nEdge = min(256, E - tileBase);
    const int total = nEdge * 28;
    const float* gp = y1 + (size_t)tileBase * 28;
    for (int j = threadIdx.x * 4; j < total; j += 1024) {
      const float4 v = *(const float4*)(gp + j);
      const int e = j / 28;
      const int cc = j - e * 28;
      float* lr = &tile[e * 29 + cc];
      lr[0] = v.x; lr[1] = v.y; lr[2] = v.z; lr[3] = v.w;
    }
    __syncthreads();
    if ((int)threadIdx.x < nEdge) {
      const float* s1 = &tile[threadIdx.x * 29];
      float acc[8];
#pragma unroll
      for (int o = 0; o < 8; o++) acc[o] = b2[o];
#pragma unroll
      for (int cc = 0; cc < 28; cc++) {
        const float s = fmaxf(s1[cc] * statsRO[72 + cc] + statsRO[100 + cc], 0.f);
#pragma unroll
        for (int o = 0; o < 8; o++) acc[o] += W2[o * 28 + cc] * s;  // uniform -> s_load
      }
      float4* yo = (float4*)(y2 + (size_t)(tileBase + threadIdx.x) * 8);
      yo[0] = make_float4(acc[0], acc[1], acc[2], acc[3]);
      yo[1] = make_float4(acc[4], acc[5], acc[6], acc[7]);
#pragma unroll
      for (int o = 0; o < 8; o++) { as[o] += acc[o]; aq[o] += acc[o] * acc[o]; }
    }
    __syncthreads();  // before next tile overwrite
  }

#pragma unroll
  for (int o = 0; o < 8; o++) {
    for (int off = 32; off; off >>= 1) {
      as[o] += __shfl_down(as[o], off);
      aq[o] += __shfl_down(aq[o], off);
    }
  }
  __shared__ float redS[4][16];
  const int wave = threadIdx.x >> 6, lane = threadIdx.x & 63;
  if (lane == 0) {
#pragma unroll
    for (int o = 0; o < 8; o++) { redS[wave][o] = as[o]; redS[wave][8 + o] = aq[o]; }
  }
  __syncthreads();
  if (threadIdx.x < 16) {
    const int t = threadIdx.x;
    atomicAdd(&statsW[56 + t], redS[0][t] + redS[1][t] + redS[2][t] + redS[3][t]);
  }
}

// K5: finalize BN2 -> scale2/shift2
__global__ void k5_fin2(const float* __restrict__ gamma, const float* __restrict__ beta,
                        float* __restrict__ stats, float invE) {
  const int c = threadIdx.x;
  if (c < 8) {
    const float mean = stats[56 + c] * invE;
    const float var = stats[64 + c] * invE - mean * mean;
    const float sc = gamma[c] * rsqrtf(var + BN_EPS);
    stats[128 + c] = sc;
    stats[136 + c] = beta[c] - mean * sc;
  }
}

// K6: out = relu(BN2(y2)) @ W3.T + b3
__global__ void k6_l3(const float* __restrict__ y2, const float* __restrict__ stats,
                      const float* __restrict__ W3, const float* __restrict__ b3,
                      float* __restrict__ out, int E) {
  const int e = blockIdx.x * blockDim.x + threadIdx.x;
  if (e >= E) return;
  const float4* p = (const float4*)(y2 + (size_t)e * 8);
  float4 a = p[0], b4 = p[1];
  float v[8] = {a.x, a.y, a.z, a.w, b4.x, b4.y, b4.z, b4.w};
  float acc = b3[0];
#pragma unroll
  for (int o = 0; o < 8; o++) {
    float s = fmaxf(v[o] * stats[128 + o] + stats[136 + o], 0.f);
    acc += W3[o] * s;
  }
  out[e] = acc;
}

extern "C" void kernel_launch(void* const* d_in, const int* in_sizes, int n_in,
                              void* d_out, int out_size, void* d_ws, size_t ws_size,
                              hipStream_t stream) {
  const float* h   = (const float*)d_in[0];
  const float* ef  = (const float*)d_in[1];
  const int* src   = (const int*)d_in[2];
  const int* dst   = (const int*)d_in[3];
  const float* W1  = (const float*)d_in[4];
  const float* b1  = (const float*)d_in[5];
  const float* g1  = (const float*)d_in[6];
  const float* be1 = (const float*)d_in[7];
  const float* W2  = (const float*)d_in[8];
  const float* b2  = (const float*)d_in[9];
  const float* g2  = (const float*)d_in[10];
  const float* be2 = (const float*)d_in[11];
  const float* W3  = (const float*)d_in[12];
  const float* b3  = (const float*)d_in[13];
  float* out = (float*)d_out;

  const int N = in_sizes[0] / 128;
  const int E = in_sizes[2];
  const float invE = 1.0f / (float)E;

  float* ws = (float*)d_ws;
  float* stats = ws;                    // 256 floats reserved
  float* Psrc = ws + 256;               // N*32, 128B-aligned rows
  float* y1 = Psrc + (size_t)N * 32;    // E*28
  float* y2 = y1 + (size_t)E * 28;      // E*8
  float* Pdst = y2;                     // overlap: Pdst dead before K4 writes y2

  const int nodeBlocks = (N + 255) / 256;
  const int nTiles = (E + 255) / 256;   // 2344
  k1_proj<<<nodeBlocks * 2, 256, 0, stream>>>(h, W1, Psrc, Pdst, stats, N);
  k2_edge<<<nTiles, 256, 0, stream>>>(Psrc, Pdst, ef, src, dst, W1, b1, y1, E);
  k2b_stats<<<1172, 224, 0, stream>>>(y1, stats, (long long)E * 28);
  k3_fin1<<<1, 32, 0, stream>>>(g1, be1, stats, invE);
  k4_l2<<<nTiles, 256, 0, stream>>>(y1, stats, W2, b2, y2, stats, E);
  k5_fin2<<<1, 64, 0, stream>>>(g2, be2, stats, invE);
  k6_l3<<<nTiles, 256, 0, stream>>>(y2, stats, W3, b3, out, E);
}

// Round 9
// 260.032 us; speedup vs baseline: 2.2149x; 1.3486x over previous
//
#include <hip/hip_runtime.h>

#define BN_EPS 1e-5f

// ws layout (floats):
//   stats[0..28)   sum1      [28..56)  ssq1
//   stats[56..64)  sum2      [64..72)  ssq2
//   stats[72..100) scale1    [100..128) shift1
//   stats[128..136) scale2   [136..144) shift2
//   Psrc at ws+256          (N*32, rows 128B-aligned, cols 28..31 zeroed)
//   y1   at Psrc + N*32     (E*28)
//   y2   at y1 + E*28       (E*8)
//   Pdst OVERLAPS y2        (N*32 <= E*8; Pdst dead before K4 writes y2)

// K1: thread-per-node, 28 channels per thread, two blocks per 256-node range.
// W half staged in LDS, read as broadcast float4 (was s_loads -> lgkm drains).
__global__ void k1_proj(const float* __restrict__ h, const float* __restrict__ W1,
                        float* __restrict__ Psrc, float* __restrict__ Pdst,
                        float* __restrict__ stats, int N) {
  __shared__ float lwk[3584];  // [c*128 + k] for this block's k-half
  if (blockIdx.x == 0 && threadIdx.x < 72) stats[threadIdx.x] = 0.f;
  const int half = blockIdx.x & 1;            // 0: src half (k 0..128), 1: dst half
  for (int j = threadIdx.x * 4; j < 3584; j += 1024) {
    const int c = j >> 7, k = j & 127;
    *(float4*)&lwk[j] = *(const float4*)(W1 + c * 268 + half * 128 + k);
  }
  __syncthreads();
  const int node = (blockIdx.x >> 1) * 256 + threadIdx.x;
  if (node >= N) return;

  const float4* __restrict__ h4 = (const float4*)(h + (size_t)node * 128);
  float acc[28];
#pragma unroll
  for (int c = 0; c < 28; c++) acc[c] = 0.f;

  for (int kk = 0; kk < 16; kk++) {
    const float4 a = h4[kk * 2];
    const float4 b = h4[kk * 2 + 1];
#pragma unroll
    for (int c = 0; c < 28; c++) {
      const float4 w0 = *(const float4*)&lwk[c * 128 + kk * 8];      // broadcast
      const float4 w1 = *(const float4*)&lwk[c * 128 + kk * 8 + 4];  // broadcast
      acc[c] += a.x * w0.x + a.y * w0.y + a.z * w0.z + a.w * w0.w
              + b.x * w1.x + b.y * w1.y + b.z * w1.z + b.w * w1.w;
    }
  }

  float4* po = (float4*)((half ? Pdst : Psrc) + (size_t)node * 32);
#pragma unroll
  for (int q = 0; q < 7; q++) {
    po[q] = make_float4(acc[q * 4], acc[q * 4 + 1], acc[q * 4 + 2], acc[q * 4 + 3]);
  }
  po[7] = make_float4(0.f, 0.f, 0.f, 0.f);  // zero pad (single-line gathers)
}

// K2 (edge-per-lane + LDS y1 tile + FUSED stats; replaces k2+k2b):
// Phase 1: thread t computes edge base+t, writes 28 ch into tile[t*28..].
// Phase 2: 224 threads write tile to y1 with CONSECUTIVE float4s (fully
// coalesced, full-line coverage -> kills round-7's +79MB partial-line write)
// AND accumulate sum/ssq: j = t*4 + i*896, 896%28==0 -> each thread's float4
// has a FIXED channel group c0=(4t)%28 -> 8 register accumulators.
// Block handles 2 tiles (grid 1172) so accumulators amortize; LDS reduce
// (8 sub-slots -> 4-way atomic contention), 56 global atomics per block.
__global__ __launch_bounds__(256)
void k2_edge(const float* __restrict__ Psrc, const float* __restrict__ Pdst,
             const float* __restrict__ ef,
             const int* __restrict__ src, const int* __restrict__ dst,
             const float* __restrict__ W1, const float* __restrict__ b1,
             float* __restrict__ y1, float* __restrict__ stats, int E) {
  __shared__ float lw[28][12];   // ef-part of W1 (cols 256..268)
  __shared__ float lb[28];
  __shared__ float tile[7168];   // 256 edges x 28 ch, unpadded (phase-2 reads
                                 // are consecutive -> conflict-free; phase-1
                                 // writes 8-way conflicted but latency-hidden)
  __shared__ float lsum[8][28], lssq[8][28];
  const int tid = threadIdx.x;
  for (int i = tid; i < 336; i += 256) lw[i / 12][i % 12] = W1[(i / 12) * 268 + 256 + (i % 12)];
  if (tid < 28) lb[tid] = b1[tid];
  if (tid < 224) { lsum[tid / 28][tid % 28] = 0.f; lssq[tid / 28][tid % 28] = 0.f; }
  __syncthreads();

  float sx = 0.f, sy = 0.f, sz = 0.f, sw = 0.f;
  float qx = 0.f, qy = 0.f, qz = 0.f, qw = 0.f;

  for (int t = 0; t < 2; t++) {
    const int base = (blockIdx.x * 2 + t) * 256;
    const int e = base + tid;
    if (e < E) {
      const int s = src[e], d = dst[e];
      const float4* __restrict__ pa4 = (const float4*)(Psrc + (size_t)s * 32);
      const float4* __restrict__ pb4 = (const float4*)(Pdst + (size_t)d * 32);
      const float4* __restrict__ e4 = (const float4*)(ef + (size_t)e * 12);
      float f[12];
#pragma unroll
      for (int q = 0; q < 3; q++) {
        const float4 v = e4[q];
        f[q * 4] = v.x; f[q * 4 + 1] = v.y; f[q * 4 + 2] = v.z; f[q * 4 + 3] = v.w;
      }
      float* tr = &tile[tid * 28];
#pragma unroll
      for (int q = 0; q < 7; q++) {
        const float4 ta = pa4[q];
        const float4 tb = pb4[q];
        float vv[4];
#pragma unroll
        for (int i2 = 0; i2 < 4; i2++) {
          const int c = q * 4 + i2;
          const float4* lw4 = (const float4*)(&lw[c][0]);  // uniform -> broadcast
          const float4 w0 = lw4[0], w1 = lw4[1], w2 = lw4[2];
          vv[i2] = lb[c]
              + f[0] * w0.x + f[1] * w0.y + f[2] * w0.z + f[3] * w0.w
              + f[4] * w1.x + f[5] * w1.y + f[6] * w1.z + f[7] * w1.w
              + f[8] * w2.x + f[9] * w2.y + f[10] * w2.z + f[11] * w2.w;
        }
        *(float4*)&tr[q * 4] = make_float4(vv[0] + ta.x + tb.x, vv[1] + ta.y + tb.y,
                                           vv[2] + ta.z + tb.z, vv[3] + ta.w + tb.w);
      }
    }
    __syncthreads();
    const int nval = min(256, E - base) * 28;   // negative if base>=E -> all skip
    if (tid < 224) {
      const size_t gbase = (size_t)base * 28;
#pragma unroll
      for (int i = 0; i < 8; i++) {
        const int jl = tid * 4 + i * 896;
        if (jl < nval) {
          const float4 v = *(const float4*)&tile[jl];        // consecutive lanes
          *(float4*)(y1 + gbase + jl) = v;                   // fully coalesced
          sx += v.x; sy += v.y; sz += v.z; sw += v.w;
          qx += v.x * v.x; qy += v.y * v.y; qz += v.z * v.z; qw += v.w * v.w;
        }
      }
    }
    __syncthreads();  // before next tile overwrite
  }

  if (tid < 224) {
    const int c0 = (tid * 4) % 28, a8 = tid / 28;   // 4-way contention per slot
    atomicAdd(&lsum[a8][c0], sx);     atomicAdd(&lssq[a8][c0], qx);
    atomicAdd(&lsum[a8][c0 + 1], sy); atomicAdd(&lssq[a8][c0 + 1], qy);
    atomicAdd(&lsum[a8][c0 + 2], sz); atomicAdd(&lssq[a8][c0 + 2], qz);
    atomicAdd(&lsum[a8][c0 + 3], sw); atomicAdd(&lssq[a8][c0 + 3], qw);
  }
  __syncthreads();
  if (tid < 28) {
    float S = 0.f, Q = 0.f;
#pragma unroll
    for (int a = 0; a < 8; a++) { S += lsum[a][tid]; Q += lssq[a][tid]; }
    atomicAdd(&stats[tid], S);
    atomicAdd(&stats[28 + tid], Q);
  }
}

// K3: finalize BN1 -> scale1/shift1
__global__ void k3_fin1(const float* __restrict__ gamma, const float* __restrict__ beta,
                        float* __restrict__ stats, float invE) {
  const int c = threadIdx.x;
  if (c < 28) {
    const float mean = stats[c] * invE;
    const float var = stats[28 + c] * invE - mean * mean;
    const float sc = gamma[c] * rsqrtf(var + BN_EPS);
    stats[72 + c] = sc;
    stats[100 + c] = beta[c] - mean * sc;
  }
}

// K4: s1 = relu(BN1(y1)); y2 = s1@W2.T + b2; accumulate stats2.
// ALL weights (W2 quads, scale/shift quads, b2) in LDS as broadcast float4 —
// the old inner loop issued 224 s_loads/edge (out-of-order SMEM -> lgkmcnt(0)
// drains, the round-4/5 pathology). Staging uses the no-division j=t*4+i*896
// mapping (coalesced global read, conflict-free LDS write).
__global__ void k4_l2(const float* __restrict__ y1, const float* __restrict__ statsRO,
                      const float* __restrict__ W2, const float* __restrict__ b2,
                      float* __restrict__ y2, float* __restrict__ statsW, int E) {
  __shared__ float tile[7168];
  __shared__ float4 w2q[8][7];   // w2q[o][q] = W2[o][4q..4q+4)
  __shared__ float4 scq[7], shq[7];
  __shared__ float lb2[8];
  const int tid = threadIdx.x;
  if (tid < 56) {
    w2q[tid / 7][tid % 7] = *(const float4*)(W2 + (tid / 7) * 28 + (tid % 7) * 4);
  } else if (tid < 63) {
    const int q = tid - 56;
    scq[q] = *(const float4*)(statsRO + 72 + q * 4);
    shq[q] = *(const float4*)(statsRO + 100 + q * 4);
  } else if (tid >= 64 && tid < 72) {
    lb2[tid - 64] = b2[tid - 64];
  }
  float as[8], aq[8];
#pragma unroll
  for (int o = 0; o < 8; o++) { as[o] = 0.f; aq[o] = 0.f; }

  for (int t = 0; t < 2; t++) {
    const int base = (blockIdx.x * 2 + t) * 256;
    const int nval = min(256, E - base) * 28;
    __syncthreads();  // weights visible (t=0) / previous compute done (t=1)
    if (tid < 224) {
      const size_t gbase = (size_t)base * 28;
#pragma unroll
      for (int i = 0; i < 8; i++) {
        const int jl = tid * 4 + i * 896;
        if (jl < nval) *(float4*)&tile[jl] = *(const float4*)(y1 + gbase + jl);
      }
    }
    __syncthreads();
    const int e = base + tid;
    if (e < E) {
      float accv[8];
#pragma unroll
      for (int o = 0; o < 8; o++) accv[o] = lb2[o];
      const float* tr = &tile[tid * 28];
#pragma unroll
      for (int q = 0; q < 7; q++) {
        const float4 sv = *(const float4*)&tr[q * 4];  // 8-way bank alias, VALU-hidden
        const float4 sc = scq[q], sh = shq[q];         // broadcast
        const float s0 = fmaxf(sv.x * sc.x + sh.x, 0.f);
        const float s1 = fmaxf(sv.y * sc.y + sh.y, 0.f);
        const float s2 = fmaxf(sv.z * sc.z + sh.z, 0.f);
        const float s3 = fmaxf(sv.w * sc.w + sh.w, 0.f);
#pragma unroll
        for (int o = 0; o < 8; o++) {
          const float4 w = w2q[o][q];                  // broadcast
          accv[o] += s0 * w.x + s1 * w.y + s2 * w.z + s3 * w.w;
        }
      }
      float4* yo = (float4*)(y2 + (size_t)e * 8);
      yo[0] = make_float4(accv[0], accv[1], accv[2], accv[3]);
      yo[1] = make_float4(accv[4], accv[5], accv[6], accv[7]);
#pragma unroll
      for (int o = 0; o < 8; o++) { as[o] += accv[o]; aq[o] += accv[o] * accv[o]; }
    }
  }

#pragma unroll
  for (int o = 0; o < 8; o++) {
    for (int off = 32; off; off >>= 1) {
      as[o] += __shfl_down(as[o], off);
      aq[o] += __shfl_down(aq[o], off);
    }
  }
  __shared__ float redS[4][16];
  const int wave = tid >> 6, lane = tid & 63;
  if (lane == 0) {
#pragma unroll
    for (int o = 0; o < 8; o++) { redS[wave][o] = as[o]; redS[wave][8 + o] = aq[o]; }
  }
  __syncthreads();
  if (tid < 16) {
    atomicAdd(&statsW[56 + tid], redS[0][tid] + redS[1][tid] + redS[2][tid] + redS[3][tid]);
  }
}

// K5: finalize BN2 -> scale2/shift2
__global__ void k5_fin2(const float* __restrict__ gamma, const float* __restrict__ beta,
                        float* __restrict__ stats, float invE) {
  const int c = threadIdx.x;
  if (c < 8) {
    const float mean = stats[56 + c] * invE;
    const float var = stats[64 + c] * invE - mean * mean;
    const float sc = gamma[c] * rsqrtf(var + BN_EPS);
    stats[128 + c] = sc;
    stats[136 + c] = beta[c] - mean * sc;
  }
}

// K6: out = relu(BN2(y2)) @ W3.T + b3
__global__ void k6_l3(const float* __restrict__ y2, const float* __restrict__ stats,
                      const float* __restrict__ W3, const float* __restrict__ b3,
                      float* __restrict__ out, int E) {
  const int e = blockIdx.x * blockDim.x + threadIdx.x;
  if (e >= E) return;
  const float4* p = (const float4*)(y2 + (size_t)e * 8);
  float4 a = p[0], b4 = p[1];
  float v[8] = {a.x, a.y, a.z, a.w, b4.x, b4.y, b4.z, b4.w};
  float acc = b3[0];
#pragma unroll
  for (int o = 0; o < 8; o++) {
    float s = fmaxf(v[o] * stats[128 + o] + stats[136 + o], 0.f);
    acc += W3[o] * s;
  }
  out[e] = acc;
}

extern "C" void kernel_launch(void* const* d_in, const int* in_sizes, int n_in,
                              void* d_out, int out_size, void* d_ws, size_t ws_size,
                              hipStream_t stream) {
  const float* h   = (const float*)d_in[0];
  const float* ef  = (const float*)d_in[1];
  const int* src   = (const int*)d_in[2];
  const int* dst   = (const int*)d_in[3];
  const float* W1  = (const float*)d_in[4];
  const float* b1  = (const float*)d_in[5];
  const float* g1  = (const float*)d_in[6];
  const float* be1 = (const float*)d_in[7];
  const float* W2  = (const float*)d_in[8];
  const float* b2  = (const float*)d_in[9];
  const float* g2  = (const float*)d_in[10];
  const float* be2 = (const float*)d_in[11];
  const float* W3  = (const float*)d_in[12];
  const float* b3  = (const float*)d_in[13];
  float* out = (float*)d_out;

  const int N = in_sizes[0] / 128;
  const int E = in_sizes[2];
  const float invE = 1.0f / (float)E;

  float* ws = (float*)d_ws;
  float* stats = ws;                    // 256 floats reserved
  float* Psrc = ws + 256;               // N*32, 128B-aligned rows
  float* y1 = Psrc + (size_t)N * 32;    // E*28
  float* y2 = y1 + (size_t)E * 28;      // E*8
  float* Pdst = y2;                     // overlap: Pdst dead before K4 writes y2

  const int nodeBlocks = (N + 255) / 256;
  const int nTiles = (E + 255) / 256;   // 2344
  const int nPair = (nTiles + 1) / 2;   // 1172 (2 tiles per block in k2/k4)
  k1_proj<<<nodeBlocks * 2, 256, 0, stream>>>(h, W1, Psrc, Pdst, stats, N);
  k2_edge<<<nPair, 256, 0, stream>>>(Psrc, Pdst, ef, src, dst, W1, b1, y1, stats, E);
  k3_fin1<<<1, 32, 0, stream>>>(g1, be1, stats, invE);
  k4_l2<<<nPair, 256, 0, stream>>>(y1, stats, W2, b2, y2, stats, E);
  k5_fin2<<<1, 64, 0, stream>>>(g2, be2, stats, invE);
  k6_l3<<<nTiles, 256, 0, stream>>>(y2, stats, W3, b3, out, E);
}